// Round 4
// baseline (458.263 us; speedup 1.0000x reference)
//
#include <hip/hip_runtime.h>
#include <hip/hip_bf16.h>

// ---------------------------------------------------------------------------
// DynamicTransformer, round 8 = round 7 + occupancy push + prepx bank fix.
//
// Round-7 result: live-set fix landed (kmain 274->152us, FETCH 366->160MB,
// WRITE 528->153MB). Counters now show MfmaUtil 8%, VALUBusy 12%, HBM 26%,
// occupancy 17.6% -> latency-bound with 2 blocks/CU; no pipe above ~35%.
//
// Round-8 changes:
//  * kmain __launch_bounds__(256,3): 3 waves/SIMD (3 blocks/CU). Live set
//    ~90 arch + 64 acc = 154 <= ~170 budget -> should fit with no spill
//    (round-3's (256,3) spill was the OLD ~230-reg structure).
//    LDS 46080*3 = 138KB <= 160KB. Kill switch: FETCH/WRITE jump = spill.
//  * prepx: xr row stride 192 -> 196 f32. Stride 192 = 0 mod 32 banks made
//    the staging ds_write_b128 bank-quad = (4qu+i)&7 (2 values, ~16-way
//    conflict); 196 gives (c+4qu+i)&7 -> all 8 quads, conflict-free.
//
//  prepw : w_in / w_out -> bf16 in exact MFMA fragment order (global)
//  prepx : x (b,c,y,x) f32 -> xT (b, y+1, x+1, c) bf16 with zero border,
//          fused per-(b,c) channel sums (for the kernel generator)
//  kgen  : exact-fp32 dynamic kernel generator -> karr[b][tap][o]
//  kmain : 16x16 aligned output tiles; h lives in f32 registers between
//          proj_in MFMA and the depthwise conv; one barrier for compute;
//          stores bounce through LDS for aligned 64B f32x4 rows.
// ---------------------------------------------------------------------------

typedef __bf16 bf16;
typedef __bf16 bf16x4 __attribute__((ext_vector_type(4)));
typedef __bf16 bf16x8 __attribute__((ext_vector_type(8)));
typedef float  f32x4  __attribute__((ext_vector_type(4)));

#define B_   8
#define DIM_ 64
#define HID_ 128
#define HW_  192
#define PW_  194            // padded width/height of xT
#define XRS_ 196            // padded xr row stride (f32) in prepx

__device__ __forceinline__ void gl_lds16(const void* g, void* l) {
  __builtin_amdgcn_global_load_lds((__attribute__((address_space(1))) void*)(g),
                                   (__attribute__((address_space(3))) void*)(l),
                                   16, 0, 0);
}

// ws layout (bytes)
#define WS_XT    0u            // 8*194*194*64*2 = 38,539,264
#define WS_XSUM  38539264u     // 512 f32
#define WS_KARR  38541312u     // 8 * 9*128 f32 = 36,864
#define WS_WIA   38578176u     // 8192 bf16 = 16,384
#define WS_WOB   38594560u     // 16384 bf16 = 32,768

// ---------------------------------------------------------------------------
// prepw: w_in -> A-frag order [cc][kk][q][m][j] (o=16cc+m, c=32kk+8q+j)
//        w_out -> B-frag order [cc][q][j64][slot8] (slot<4: w_out[j][16cc+4q+slot], else 0)
// 24576 threads: 8192 for wiA, 16384 for woB.
// ---------------------------------------------------------------------------
__global__ __launch_bounds__(256) void dt_prepw(const float* __restrict__ w_in,
                                                const float* __restrict__ w_out,
                                                bf16* __restrict__ wiA,
                                                bf16* __restrict__ woB) {
  int i = blockIdx.x * 256 + threadIdx.x;          // 0..24575
  if (i < 8192) {
    int j = i & 7, m = (i >> 3) & 15, q = (i >> 7) & 3, kk = (i >> 9) & 1, cc = i >> 10;
    int o = cc * 16 + m, c = kk * 32 + q * 8 + j;
    wiA[i] = (bf16)w_in[o * DIM_ + c];
  } else {
    int i2 = i - 8192;                             // 0..16383
    int sl = i2 & 7, j = (i2 >> 3) & 63, q = (i2 >> 9) & 3, cc = i2 >> 11;  // cc 0..7
    float v = (sl < 4) ? w_out[j * HID_ + cc * 16 + q * 4 + sl] : 0.f;
    woB[i2] = (bf16)v;
  }
}

// ---------------------------------------------------------------------------
// prepx: one block per (b, padded row yy). Interior rows: transpose 64x192
// f32 -> 192 px * 64c bf16 (via LDS), plus channel partial sums -> atomicAdd.
// Border rows / cols written as zeros. xr stride padded to 196 f32 so the
// staging ds_write_b128 spreads over all 8 bank-quads.
// ---------------------------------------------------------------------------
__global__ __launch_bounds__(256) void dt_prepx(const float* __restrict__ x,
                                                bf16* __restrict__ xT,
                                                float* __restrict__ xsum) {
  const int yy = blockIdx.x, b = blockIdx.y, t = threadIdx.x;
  bf16* xtrow = xT + ((size_t)(b * PW_ + yy)) * PW_ * DIM_;
  const bf16x8 z8 = {(bf16)0.f,(bf16)0.f,(bf16)0.f,(bf16)0.f,
                     (bf16)0.f,(bf16)0.f,(bf16)0.f,(bf16)0.f};
  if (yy == 0 || yy == PW_ - 1) {
    if (t < PW_) {
      bf16* dst = xtrow + t * DIM_;
#pragma unroll
      for (int c8 = 0; c8 < 8; ++c8) *(bf16x8*)(dst + c8 * 8) = z8;
    }
    return;
  }
  const int y = yy - 1;
  __shared__ float xr[DIM_ * XRS_];                // [c][px], stride 196
  const int c = t >> 2, qu = t & 3;
  const float4* rp = (const float4*)(x + ((size_t)(b * DIM_ + c) * HW_ + y) * HW_) + qu * 12;
  float s = 0.f;
#pragma unroll
  for (int i = 0; i < 12; ++i) {
    float4 v = rp[i];
    s += (v.x + v.y) + (v.z + v.w);
    ((float4*)xr)[c * 49 + qu * 12 + i] = v;       // 49 float4 = 196 f32 row
  }
  s += __shfl_down(s, 2);
  s += __shfl_down(s, 1);
  if ((t & 3) == 0) atomicAdd(xsum + b * DIM_ + c, s);
  __syncthreads();
  if (t < HW_) {
    const int px = t;
    bf16* dst = xtrow + (px + 1) * DIM_;
#pragma unroll
    for (int c8 = 0; c8 < 8; ++c8) {
      bf16x8 pk;
#pragma unroll
      for (int j2 = 0; j2 < 8; ++j2) pk[j2] = (bf16)xr[(c8 * 8 + j2) * XRS_ + px];
      *(bf16x8*)(dst + c8 * 8) = pk;
    }
  } else if (t == HW_ || t == HW_ + 1) {           // border cols xx=0, xx=193
    bf16* dst = xtrow + (size_t)(t - HW_) * (PW_ - 1) * DIM_;
#pragma unroll
    for (int c8 = 0; c8 < 8; ++c8) *(bf16x8*)(dst + c8 * 8) = z8;
  }
}

// ---------------------------------------------------------------------------
// kgen: exact fp32. karr[b][tap][o], tap-major so kmain reads f32x4 over o.
// ---------------------------------------------------------------------------
__global__ __launch_bounds__(128) void dt_kgen(
    const float* __restrict__ xsum, const float* __restrict__ w_in,
    const float* __restrict__ b_in, const float* __restrict__ wg1,
    const float* __restrict__ bg1, const float* __restrict__ wg2,
    const float* __restrict__ bg2, float* __restrict__ karr) {
  const int b = blockIdx.x, t = threadIdx.x;
  __shared__ float xm[DIM_], hm[HID_], g[HID_];
  if (t < DIM_) xm[t] = xsum[b * DIM_ + t] * (1.f / (HW_ * HW_));
  __syncthreads();
  {
    float a = b_in[t];
    const float* w = w_in + t * DIM_;
    for (int c = 0; c < DIM_; ++c) a += w[c] * xm[c];
    hm[t] = a;
  }
  __syncthreads();
  {
    float a = bg1[t];
    const float* w = wg1 + t * HID_;
    for (int c = 0; c < HID_; ++c) a += w[c] * hm[c];
    g[t] = a > 0.f ? a : 0.f;
  }
  __syncthreads();
  for (int tp = 0; tp < 9; ++tp) {
    float s = bg2[t * 9 + tp];
    const float* w2 = wg2 + (size_t)(t * 9 + tp) * HID_;
    for (int c = 0; c < HID_; ++c) s += w2[c] * g[c];
    karr[b * 1152 + tp * HID_ + t] = s;
  }
}

// ---------------------------------------------------------------------------
// kmain. Grid (12,12,8), 256 threads (4 waves). Wave wv owns out rows
// 4wv..4wv+3 of the tile (h tile rows 4wv..4wv+5).
// LDS: [0,41472) x_s: 18 rows x (kk2 x q4 x px18) 16B chunks
//      [41472,46080) karr f32 [tap][128]
//      store bounce aliases [0,34048) after compute barrier.
// __launch_bounds__(256,3): 3 waves/SIMD = 3 blocks/CU. Live set ~90 arch
// + 64 acc AGPR = ~154 <= ~170 unified budget -> no spill expected.
// LDS 3*46080 = 138KB <= 160KB.
// ---------------------------------------------------------------------------
#define XROWB 2304
#define KOFF  41472

// h-row macro: proj_in MFMAs for the 3 shifted column windows of smem row
// (wv*4+RR), plus wave-uniform-row masked bias add. Declares HL/HM/HR.
#define HROW(RR, HL, HM, HR)                                                  \
  f32x4 HL, HM, HR;                                                           \
  do {                                                                        \
    const char* rbase_ = smem + (wv * 4 + (RR)) * XROWB + q * 288 + m * 16;   \
    const f32x4 z_ = 0.f;                                                     \
    bf16x8 xa_ = *(const bf16x8*)(rbase_);                                    \
    bf16x8 xb_ = *(const bf16x8*)(rbase_ + 1152);                             \
    HL = __builtin_amdgcn_mfma_f32_16x16x32_bf16(wa0, xa_, z_, 0, 0, 0);      \
    HL = __builtin_amdgcn_mfma_f32_16x16x32_bf16(wa1, xb_, HL, 0, 0, 0);      \
    xa_ = *(const bf16x8*)(rbase_ + 16);                                      \
    xb_ = *(const bf16x8*)(rbase_ + 1152 + 16);                               \
    HM = __builtin_amdgcn_mfma_f32_16x16x32_bf16(wa0, xa_, z_, 0, 0, 0);      \
    HM = __builtin_amdgcn_mfma_f32_16x16x32_bf16(wa1, xb_, HM, 0, 0, 0);      \
    xa_ = *(const bf16x8*)(rbase_ + 32);                                      \
    xb_ = *(const bf16x8*)(rbase_ + 1152 + 32);                               \
    HR = __builtin_amdgcn_mfma_f32_16x16x32_bf16(wa0, xa_, z_, 0, 0, 0);      \
    HR = __builtin_amdgcn_mfma_f32_16x16x32_bf16(wa1, xb_, HR, 0, 0, 0);      \
    if ((unsigned)(rowg0 + wv * 4 + (RR)) < (unsigned)HW_) {                  \
      HL += bin4 * mL; HM += bin4 * mM; HR += bin4 * mR;                      \
    }                                                                         \
  } while (0)

// read one 3-tap row (dy = T/3) of the dynamic kernel from LDS (broadcast)
#define TAPROW(T, K0, K1, K2)                                                 \
  const f32x4 K0 = *(const f32x4*)(kvp + (T) * HID_);                         \
  const f32x4 K1 = *(const f32x4*)(kvp + ((T) + 1) * HID_);                   \
  const f32x4 K2 = *(const f32x4*)(kvp + ((T) + 2) * HID_)

#define CINIT(Y, HL, HM, HR)                                                  \
  do { TAPROW(0, k0_, k1_, k2_);                                              \
       Y = k0_ * HL + k1_ * HM + k2_ * HR; } while (0)

#define CMID(Y, HL, HM, HR)                                                   \
  do { TAPROW(3, k3_, k4_, k5_);                                              \
       Y += k3_ * HL; Y += k4_ * HM; Y += k5_ * HR; } while (0)

#define CEMIT(PY, Y, HL, HM, HR)                                              \
  do { TAPROW(6, k6_, k7_, k8_);                                              \
       f32x4 v_ = Y + k6_ * HL + k7_ * HM + k8_ * HR;                         \
       float a0_ = v_[0], a1_ = v_[1], a2_ = v_[2], a3_ = v_[3];              \
       bf16x8 af_ = {(bf16)fmaxf(a0_, 0.1f * a0_),                            \
                     (bf16)fmaxf(a1_, 0.1f * a1_),                            \
                     (bf16)fmaxf(a2_, 0.1f * a2_),                            \
                     (bf16)fmaxf(a3_, 0.1f * a3_),                            \
                     (bf16)0.f, (bf16)0.f, (bf16)0.f, (bf16)0.f};             \
       acc3[PY][0] = __builtin_amdgcn_mfma_f32_16x16x32_bf16(af_, wb0, acc3[PY][0], 0, 0, 0); \
       acc3[PY][1] = __builtin_amdgcn_mfma_f32_16x16x32_bf16(af_, wb1, acc3[PY][1], 0, 0, 0); \
       acc3[PY][2] = __builtin_amdgcn_mfma_f32_16x16x32_bf16(af_, wb2, acc3[PY][2], 0, 0, 0); \
       acc3[PY][3] = __builtin_amdgcn_mfma_f32_16x16x32_bf16(af_, wb3, acc3[PY][3], 0, 0, 0); \
  } while (0)

__global__ __launch_bounds__(256, 3) void dt_kmain(
    const bf16* __restrict__ xT, const bf16* __restrict__ wiA,
    const bf16* __restrict__ woB, const float* __restrict__ karr,
    const float* __restrict__ b_in, const float* __restrict__ b_out,
    float* __restrict__ out) {
  __shared__ __attribute__((aligned(16))) char smem[46080];
  const int t = threadIdx.x;
  const int wv = t >> 6, lane = t & 63;
  const int q = lane >> 4, m = lane & 15;
  const int tx = blockIdx.x, ty = blockIdx.y, b = blockIdx.z;

  // ---- stage x tile + karr via global_load_lds ---------------------------
  {
    const char* xbase = (const char*)xT +
        ((size_t)(b * PW_ + ty * 16) * PW_ + tx * 16) * (DIM_ * 2);
    for (int rr = wv; rr < 18; rr += 4) {
      const char* grow = xbase + (size_t)rr * (PW_ * DIM_ * 2);
      char* lrow = smem + rr * XROWB;
#pragma unroll
      for (int p = 0; p < 3; ++p) {
        int idx = p * 64 + lane;
        if (idx < 144) {
          int kq = (idx * 57) >> 10;        // idx / 18
          int px = idx - kq * 18;
          int goff = px * 128 + (kq >> 2) * 64 + (kq & 3) * 16;
          gl_lds16(grow + goff, lrow + p * 1024);
        }
      }
    }
    const char* kg = (const char*)karr + b * 4608;
    gl_lds16(kg + (wv * 64 + lane) * 16, smem + KOFF + wv * 1024);
    if (wv == 0 && lane < 32)
      gl_lds16(kg + (256 + lane) * 16, smem + KOFF + 4096);
  }
  __syncthreads();

  const int rowg0 = ty * 16 - 1;
  const int colg0 = tx * 16 - 1;
  const float mL = ((unsigned)(colg0 + 0 + m) < (unsigned)HW_) ? 1.f : 0.f;
  const float mM = ((unsigned)(colg0 + 1 + m) < (unsigned)HW_) ? 1.f : 0.f;
  const float mR = ((unsigned)(colg0 + 2 + m) < (unsigned)HW_) ? 1.f : 0.f;

  f32x4 acc3[4][4];
#pragma unroll
  for (int a = 0; a < 4; ++a)
#pragma unroll
    for (int n = 0; n < 4; ++n) acc3[a][n] = 0.f;

  const float* karrL = (const float*)(smem + KOFF);

  for (int cc = 0; cc < 8; ++cc) {
    const bf16x8 wa0 = *(const bf16x8*)((const char*)wiA + ((cc * 2 + 0) * 4 + q) * 256 + m * 16);
    const bf16x8 wa1 = *(const bf16x8*)((const char*)wiA + ((cc * 2 + 1) * 4 + q) * 256 + m * 16);
    const bf16x8 wb0 = *(const bf16x8*)((const char*)woB + (((cc * 4 + q) * 64) + 0 * 16 + m) * 16);
    const bf16x8 wb1 = *(const bf16x8*)((const char*)woB + (((cc * 4 + q) * 64) + 1 * 16 + m) * 16);
    const bf16x8 wb2 = *(const bf16x8*)((const char*)woB + (((cc * 4 + q) * 64) + 2 * 16 + m) * 16);
    const bf16x8 wb3 = *(const bf16x8*)((const char*)woB + (((cc * 4 + q) * 64) + 3 * 16 + m) * 16);
    const f32x4 bin4 = *(const f32x4*)(b_in + cc * 16 + q * 4);
    const float* kvp = karrL + cc * 16 + q * 4;   // tap tp lives at kvp+tp*128

    // Hand-unrolled 6-row stream: h row rr feeds outputs py=rr-2..rr as
    // tap-row dy=rr-py. All indices literal; y0..y3 are named registers.
    f32x4 y0, y1, y2, y3;
    HROW(0, hL0, hM0, hR0);
    CINIT(y0, hL0, hM0, hR0);
    HROW(1, hL1, hM1, hR1);
    CMID (y0, hL1, hM1, hR1);
    CINIT(y1, hL1, hM1, hR1);
    HROW(2, hL2, hM2, hR2);
    CEMIT(0, y0, hL2, hM2, hR2);
    CMID (y1, hL2, hM2, hR2);
    CINIT(y2, hL2, hM2, hR2);
    HROW(3, hL3, hM3, hR3);
    CEMIT(1, y1, hL3, hM3, hR3);
    CMID (y2, hL3, hM3, hR3);
    CINIT(y3, hL3, hM3, hR3);
    HROW(4, hL4, hM4, hR4);
    CEMIT(2, y2, hL4, hM4, hR4);
    CMID (y3, hL4, hM4, hR4);
    HROW(5, hL5, hM5, hR5);
    CEMIT(3, y3, hL5, hM5, hR5);
  }
  __syncthreads();          // x_s / karr dead; bounce region reuses smem

  // ---- store via LDS bounce: aligned 64B f32x4 rows ----------------------
  float* smemF = (float*)smem;                      // [j][132] f32, halves of 8 rows
  const int c4 = t & 3, js = (t >> 2) & 63;
  const float bo = b_out[js];
  float* obase = out + ((size_t)(b * DIM_ + js) * HW_ + (ty * 16)) * HW_ + tx * 16 + c4 * 4;
#pragma unroll
  for (int half = 0; half < 2; ++half) {
    if ((wv >> 1) == half) {
#pragma unroll
      for (int py = 0; py < 4; ++py) {
        const int lrow = (wv * 4 + py) & 7;
#pragma unroll
        for (int nt = 0; nt < 4; ++nt)
          *(f32x4*)(smemF + (nt * 16 + m) * 132 + lrow * 16 + q * 4) = acc3[py][nt];
      }
    }
    __syncthreads();
#pragma unroll
    for (int lrow = 0; lrow < 8; ++lrow) {
      f32x4 v = *(const f32x4*)(smemF + js * 132 + lrow * 16 + c4 * 4);
      v += bo;
      *(f32x4*)(obase + (size_t)(half * 8 + lrow) * HW_) = v;
    }
    __syncthreads();
  }
}

// ---------------------------------------------------------------------------
extern "C" void kernel_launch(void* const* d_in, const int* in_sizes, int n_in,
                              void* d_out, int out_size, void* d_ws,
                              size_t ws_size, hipStream_t stream) {
  const float* x     = (const float*)d_in[0];
  const float* w_in  = (const float*)d_in[1];
  const float* b_in  = (const float*)d_in[2];
  const float* wg1   = (const float*)d_in[3];
  const float* bg1   = (const float*)d_in[4];
  const float* wg2   = (const float*)d_in[5];
  const float* bg2   = (const float*)d_in[6];
  const float* w_out = (const float*)d_in[7];
  const float* b_out = (const float*)d_in[8];
  float* out = (float*)d_out;

  char* ws = (char*)d_ws;
  bf16*  xT   = (bf16*)(ws + WS_XT);
  float* xsum = (float*)(ws + WS_XSUM);
  float* karr = (float*)(ws + WS_KARR);
  bf16*  wiA  = (bf16*)(ws + WS_WIA);
  bf16*  woB  = (bf16*)(ws + WS_WOB);

  hipMemsetAsync(xsum, 0, B_ * DIM_ * sizeof(float), stream);
  dt_prepw<<<dim3(96), dim3(256), 0, stream>>>(w_in, w_out, wiA, woB);
  dt_prepx<<<dim3(PW_, B_), dim3(256), 0, stream>>>(x, xT, xsum);
  dt_kgen<<<dim3(B_), dim3(128), 0, stream>>>(xsum, w_in, b_in, wg1, bg1, wg2,
                                              bg2, karr);
  dt_kmain<<<dim3(12, 12, B_), dim3(256), 0, stream>>>(xT, wiA, woB, karr,
                                                       b_in, b_out, out);
}

// Round 5
// 329.695 us; speedup vs baseline: 1.3900x; 1.3900x over previous
//
#include <hip/hip_runtime.h>
#include <hip/hip_bf16.h>

// ---------------------------------------------------------------------------
// DynamicTransformer, round 9 = round 7 (proven 152us kmain) + XCD pair-swizzle
// store fix + kgen widen + dispatch fold. Round-8's (256,3) spilled exactly as
// the kill condition predicted (VGPR 84, FETCH 737MB) -> 192 total regs pins
// this structure at 2 blocks/CU; occupancy lever abandoned.
//
// kmain store diagnosis: 16-px tiles store 64B half-lines; adjacent tx blocks
// (the two halves of each 128B line) round-robin onto DIFFERENT XCDs' L2s ->
// each half does a 128B write-allocate fetch + 128B writeback = WRITE 2x ideal
// (153 vs 75.5MB) + ~105MB RMW FETCH. Fix: remap block->work so raw IDs
// differing by 8 (same XCD under %8 round-robin) own tx=2p and tx=2p+1.
// Both halves merge in one L2 -> 1 fetch + 1 full-line writeback.
//
//  prepw : w_in / w_out -> bf16 MFMA fragment order; also zeros xsum
//  prepx : x -> xT (b, y+1, x+1, c) bf16, zero border, fused channel sums
//          (xr stride 196 f32: staging ds_write spread over all bank quads)
//  kgen  : 256-thread, float4 dots; exact-fp32 generator -> karr[b][tap][o]
//  kmain : UNCHANGED hot loop vs round 7; only block-index decode + same
//          store bounce. __launch_bounds__(256,2).
// ---------------------------------------------------------------------------

typedef __bf16 bf16;
typedef __bf16 bf16x4 __attribute__((ext_vector_type(4)));
typedef __bf16 bf16x8 __attribute__((ext_vector_type(8)));
typedef float  f32x4  __attribute__((ext_vector_type(4)));

#define B_   8
#define DIM_ 64
#define HID_ 128
#define HW_  192
#define PW_  194            // padded width/height of xT
#define XRS_ 196            // padded xr row stride (f32) in prepx

__device__ __forceinline__ void gl_lds16(const void* g, void* l) {
  __builtin_amdgcn_global_load_lds((__attribute__((address_space(1))) void*)(g),
                                   (__attribute__((address_space(3))) void*)(l),
                                   16, 0, 0);
}

// ws layout (bytes)
#define WS_XT    0u            // 8*194*194*64*2 = 38,539,264
#define WS_XSUM  38539264u     // 512 f32
#define WS_KARR  38541312u     // 8 * 9*128 f32 = 36,864
#define WS_WIA   38578176u     // 8192 bf16 = 16,384
#define WS_WOB   38594560u     // 16384 bf16 = 32,768

// ---------------------------------------------------------------------------
// prepw: w_in -> A-frag order [cc][kk][q][m][j] (o=16cc+m, c=32kk+8q+j)
//        w_out -> B-frag order [cc][q][j64][slot8]
// Block 0 additionally zeros xsum (replaces the hipMemsetAsync dispatch;
// prepx's atomics are stream-ordered after prepw completes).
// ---------------------------------------------------------------------------
__global__ __launch_bounds__(256) void dt_prepw(const float* __restrict__ w_in,
                                                const float* __restrict__ w_out,
                                                bf16* __restrict__ wiA,
                                                bf16* __restrict__ woB,
                                                float* __restrict__ xsum) {
  if (blockIdx.x == 0) {
    xsum[threadIdx.x] = 0.f;
    xsum[threadIdx.x + 256] = 0.f;
  }
  int i = blockIdx.x * 256 + threadIdx.x;          // 0..24575
  if (i < 8192) {
    int j = i & 7, m = (i >> 3) & 15, q = (i >> 7) & 3, kk = (i >> 9) & 1, cc = i >> 10;
    int o = cc * 16 + m, c = kk * 32 + q * 8 + j;
    wiA[i] = (bf16)w_in[o * DIM_ + c];
  } else {
    int i2 = i - 8192;                             // 0..16383
    int sl = i2 & 7, j = (i2 >> 3) & 63, q = (i2 >> 9) & 3, cc = i2 >> 11;  // cc 0..7
    float v = (sl < 4) ? w_out[j * HID_ + cc * 16 + q * 4 + sl] : 0.f;
    woB[i2] = (bf16)v;
  }
}

// ---------------------------------------------------------------------------
// prepx: one block per (b, padded row yy). Interior rows: transpose 64x192
// f32 -> 192 px * 64c bf16 (via LDS), plus channel partial sums -> atomicAdd.
// Border rows / cols written as zeros. xr stride padded to 196 f32 so the
// staging ds_write_b128 spreads over all 8 bank-quads.
// ---------------------------------------------------------------------------
__global__ __launch_bounds__(256) void dt_prepx(const float* __restrict__ x,
                                                bf16* __restrict__ xT,
                                                float* __restrict__ xsum) {
  const int yy = blockIdx.x, b = blockIdx.y, t = threadIdx.x;
  bf16* xtrow = xT + ((size_t)(b * PW_ + yy)) * PW_ * DIM_;
  const bf16x8 z8 = {(bf16)0.f,(bf16)0.f,(bf16)0.f,(bf16)0.f,
                     (bf16)0.f,(bf16)0.f,(bf16)0.f,(bf16)0.f};
  if (yy == 0 || yy == PW_ - 1) {
    if (t < PW_) {
      bf16* dst = xtrow + t * DIM_;
#pragma unroll
      for (int c8 = 0; c8 < 8; ++c8) *(bf16x8*)(dst + c8 * 8) = z8;
    }
    return;
  }
  const int y = yy - 1;
  __shared__ float xr[DIM_ * XRS_];                // [c][px], stride 196
  const int c = t >> 2, qu = t & 3;
  const float4* rp = (const float4*)(x + ((size_t)(b * DIM_ + c) * HW_ + y) * HW_) + qu * 12;
  float s = 0.f;
#pragma unroll
  for (int i = 0; i < 12; ++i) {
    float4 v = rp[i];
    s += (v.x + v.y) + (v.z + v.w);
    ((float4*)xr)[c * 49 + qu * 12 + i] = v;       // 49 float4 = 196 f32 row
  }
  s += __shfl_down(s, 2);
  s += __shfl_down(s, 1);
  if ((t & 3) == 0) atomicAdd(xsum + b * DIM_ + c, s);
  __syncthreads();
  if (t < HW_) {
    const int px = t;
    bf16* dst = xtrow + (px + 1) * DIM_;
#pragma unroll
    for (int c8 = 0; c8 < 8; ++c8) {
      bf16x8 pk;
#pragma unroll
      for (int j2 = 0; j2 < 8; ++j2) pk[j2] = (bf16)xr[(c8 * 8 + j2) * XRS_ + px];
      *(bf16x8*)(dst + c8 * 8) = pk;
    }
  } else if (t == HW_ || t == HW_ + 1) {           // border cols xx=0, xx=193
    bf16* dst = xtrow + (size_t)(t - HW_) * (PW_ - 1) * DIM_;
#pragma unroll
    for (int c8 = 0; c8 < 8; ++c8) *(bf16x8*)(dst + c8 * 8) = z8;
  }
}

// ---------------------------------------------------------------------------
// kgen: exact fp32, 256 threads, float4 dot products. Sits serially on the
// critical path (prepx -> kgen -> kmain) on only 8 blocks, so minimize its
// latency. karr[b][tap][o], tap-major so kmain reads f32x4 over o.
// ---------------------------------------------------------------------------
__global__ __launch_bounds__(256) void dt_kgen(
    const float* __restrict__ xsum, const float* __restrict__ w_in,
    const float* __restrict__ b_in, const float* __restrict__ wg1,
    const float* __restrict__ bg1, const float* __restrict__ wg2,
    const float* __restrict__ bg2, float* __restrict__ karr) {
  const int b = blockIdx.x, t = threadIdx.x;
  __shared__ float xm[DIM_], hm[HID_], g[HID_];
  if (t < DIM_) xm[t] = xsum[b * DIM_ + t] * (1.f / (HW_ * HW_));
  __syncthreads();
  if (t < HID_) {
    float a = b_in[t];
    const float4* w = (const float4*)(w_in + t * DIM_);
#pragma unroll
    for (int c4 = 0; c4 < DIM_ / 4; ++c4) {
      float4 wv = w[c4];
      a += wv.x * xm[c4 * 4] + wv.y * xm[c4 * 4 + 1] +
           wv.z * xm[c4 * 4 + 2] + wv.w * xm[c4 * 4 + 3];
    }
    hm[t] = a;
  }
  __syncthreads();
  if (t < HID_) {
    float a = bg1[t];
    const float4* w = (const float4*)(wg1 + t * HID_);
#pragma unroll
    for (int c4 = 0; c4 < HID_ / 4; ++c4) {
      float4 wv = w[c4];
      a += wv.x * hm[c4 * 4] + wv.y * hm[c4 * 4 + 1] +
           wv.z * hm[c4 * 4 + 2] + wv.w * hm[c4 * 4 + 3];
    }
    g[t] = fmaxf(a, 0.f);
  }
  __syncthreads();
  for (int o = t; o < HID_ * 9; o += 256) {        // o = ch*9 + tp
    float s = bg2[o];
    const float4* w2 = (const float4*)(wg2 + (size_t)o * HID_);
#pragma unroll
    for (int c4 = 0; c4 < HID_ / 4; ++c4) {
      float4 wv = w2[c4];
      s += wv.x * g[c4 * 4] + wv.y * g[c4 * 4 + 1] +
           wv.z * g[c4 * 4 + 2] + wv.w * g[c4 * 4 + 3];
    }
    int ch = o / 9, tp = o - ch * 9;
    karr[b * 1152 + tp * HID_ + ch] = s;
  }
}

// ---------------------------------------------------------------------------
// kmain. Grid (12,12,8) raw; block->work remapped so raw IDs differing by 8
// (same XCD under %8 round-robin dispatch) own tx=2p and tx=2p+1 -> the two
// 64B halves of each 128B output line merge in ONE XCD's L2 (1 fetch + 1
// full-line writeback instead of 2x RMW).
// 256 threads (4 waves). Wave wv owns out rows 4wv..4wv+3 (h rows 4wv..4wv+5).
// LDS: [0,41472) x_s; [41472,46080) karr; store bounce aliases [0,34048).
// __launch_bounds__(256,2): 192 total regs (128 arch + 64 acc) = the proven
// no-spill config; (256,3) spills (round 8: VGPR 84, FETCH 737MB).
// ---------------------------------------------------------------------------
#define XROWB 2304
#define KOFF  41472

// h-row macro: proj_in MFMAs for the 3 shifted column windows of smem row
// (wv*4+RR), plus wave-uniform-row masked bias add. Declares HL/HM/HR.
#define HROW(RR, HL, HM, HR)                                                  \
  f32x4 HL, HM, HR;                                                           \
  do {                                                                        \
    const char* rbase_ = smem + (wv * 4 + (RR)) * XROWB + q * 288 + m * 16;   \
    const f32x4 z_ = 0.f;                                                     \
    bf16x8 xa_ = *(const bf16x8*)(rbase_);                                    \
    bf16x8 xb_ = *(const bf16x8*)(rbase_ + 1152);                             \
    HL = __builtin_amdgcn_mfma_f32_16x16x32_bf16(wa0, xa_, z_, 0, 0, 0);      \
    HL = __builtin_amdgcn_mfma_f32_16x16x32_bf16(wa1, xb_, HL, 0, 0, 0);      \
    xa_ = *(const bf16x8*)(rbase_ + 16);                                      \
    xb_ = *(const bf16x8*)(rbase_ + 1152 + 16);                               \
    HM = __builtin_amdgcn_mfma_f32_16x16x32_bf16(wa0, xa_, z_, 0, 0, 0);      \
    HM = __builtin_amdgcn_mfma_f32_16x16x32_bf16(wa1, xb_, HM, 0, 0, 0);      \
    xa_ = *(const bf16x8*)(rbase_ + 32);                                      \
    xb_ = *(const bf16x8*)(rbase_ + 1152 + 32);                               \
    HR = __builtin_amdgcn_mfma_f32_16x16x32_bf16(wa0, xa_, z_, 0, 0, 0);      \
    HR = __builtin_amdgcn_mfma_f32_16x16x32_bf16(wa1, xb_, HR, 0, 0, 0);      \
    if ((unsigned)(rowg0 + wv * 4 + (RR)) < (unsigned)HW_) {                  \
      HL += bin4 * mL; HM += bin4 * mM; HR += bin4 * mR;                      \
    }                                                                         \
  } while (0)

// read one 3-tap row (dy = T/3) of the dynamic kernel from LDS (broadcast)
#define TAPROW(T, K0, K1, K2)                                                 \
  const f32x4 K0 = *(const f32x4*)(kvp + (T) * HID_);                         \
  const f32x4 K1 = *(const f32x4*)(kvp + ((T) + 1) * HID_);                   \
  const f32x4 K2 = *(const f32x4*)(kvp + ((T) + 2) * HID_)

#define CINIT(Y, HL, HM, HR)                                                  \
  do { TAPROW(0, k0_, k1_, k2_);                                              \
       Y = k0_ * HL + k1_ * HM + k2_ * HR; } while (0)

#define CMID(Y, HL, HM, HR)                                                   \
  do { TAPROW(3, k3_, k4_, k5_);                                              \
       Y += k3_ * HL; Y += k4_ * HM; Y += k5_ * HR; } while (0)

#define CEMIT(PY, Y, HL, HM, HR)                                              \
  do { TAPROW(6, k6_, k7_, k8_);                                              \
       f32x4 v_ = Y + k6_ * HL + k7_ * HM + k8_ * HR;                         \
       float a0_ = v_[0], a1_ = v_[1], a2_ = v_[2], a3_ = v_[3];              \
       bf16x8 af_ = {(bf16)fmaxf(a0_, 0.1f * a0_),                            \
                     (bf16)fmaxf(a1_, 0.1f * a1_),                            \
                     (bf16)fmaxf(a2_, 0.1f * a2_),                            \
                     (bf16)fmaxf(a3_, 0.1f * a3_),                            \
                     (bf16)0.f, (bf16)0.f, (bf16)0.f, (bf16)0.f};             \
       acc3[PY][0] = __builtin_amdgcn_mfma_f32_16x16x32_bf16(af_, wb0, acc3[PY][0], 0, 0, 0); \
       acc3[PY][1] = __builtin_amdgcn_mfma_f32_16x16x32_bf16(af_, wb1, acc3[PY][1], 0, 0, 0); \
       acc3[PY][2] = __builtin_amdgcn_mfma_f32_16x16x32_bf16(af_, wb2, acc3[PY][2], 0, 0, 0); \
       acc3[PY][3] = __builtin_amdgcn_mfma_f32_16x16x32_bf16(af_, wb3, acc3[PY][3], 0, 0, 0); \
  } while (0)

__global__ __launch_bounds__(256, 2) void dt_kmain(
    const bf16* __restrict__ xT, const bf16* __restrict__ wiA,
    const bf16* __restrict__ woB, const float* __restrict__ karr,
    const float* __restrict__ b_in, const float* __restrict__ b_out,
    float* __restrict__ out) {
  __shared__ __attribute__((aligned(16))) char smem[46080];
  const int t = threadIdx.x;
  const int wv = t >> 6, lane = t & 63;
  const int q = lane >> 4, m = lane & 15;

  // XCD pair-swizzle: raw IDs {r, r+8} (same XCD) -> halves 0/1 of pair p.
  const int raw = blockIdx.x + 12 * blockIdx.y + 144 * blockIdx.z;  // 0..1151
  const int hf  = (raw >> 3) & 1;
  const int p   = (raw & 7) + ((raw >> 4) << 3);                    // 0..575
  const int pm6 = p % 6;
  const int tx  = 2 * pm6 + hf;
  const int ty  = (p / 6) % 12;
  const int b   = p / 72;

  // ---- stage x tile + karr via global_load_lds ---------------------------
  {
    const char* xbase = (const char*)xT +
        ((size_t)(b * PW_ + ty * 16) * PW_ + tx * 16) * (DIM_ * 2);
    for (int rr = wv; rr < 18; rr += 4) {
      const char* grow = xbase + (size_t)rr * (PW_ * DIM_ * 2);
      char* lrow = smem + rr * XROWB;
#pragma unroll
      for (int pp = 0; pp < 3; ++pp) {
        int idx = pp * 64 + lane;
        if (idx < 144) {
          int kq = (idx * 57) >> 10;        // idx / 18
          int px = idx - kq * 18;
          int goff = px * 128 + (kq >> 2) * 64 + (kq & 3) * 16;
          gl_lds16(grow + goff, lrow + pp * 1024);
        }
      }
    }
    const char* kg = (const char*)karr + b * 4608;
    gl_lds16(kg + (wv * 64 + lane) * 16, smem + KOFF + wv * 1024);
    if (wv == 0 && lane < 32)
      gl_lds16(kg + (256 + lane) * 16, smem + KOFF + 4096);
  }
  __syncthreads();

  const int rowg0 = ty * 16 - 1;
  const int colg0 = tx * 16 - 1;
  const float mL = ((unsigned)(colg0 + 0 + m) < (unsigned)HW_) ? 1.f : 0.f;
  const float mM = ((unsigned)(colg0 + 1 + m) < (unsigned)HW_) ? 1.f : 0.f;
  const float mR = ((unsigned)(colg0 + 2 + m) < (unsigned)HW_) ? 1.f : 0.f;

  f32x4 acc3[4][4];
#pragma unroll
  for (int a = 0; a < 4; ++a)
#pragma unroll
    for (int n = 0; n < 4; ++n) acc3[a][n] = 0.f;

  const float* karrL = (const float*)(smem + KOFF);

  for (int cc = 0; cc < 8; ++cc) {
    const bf16x8 wa0 = *(const bf16x8*)((const char*)wiA + ((cc * 2 + 0) * 4 + q) * 256 + m * 16);
    const bf16x8 wa1 = *(const bf16x8*)((const char*)wiA + ((cc * 2 + 1) * 4 + q) * 256 + m * 16);
    const bf16x8 wb0 = *(const bf16x8*)((const char*)woB + (((cc * 4 + q) * 64) + 0 * 16 + m) * 16);
    const bf16x8 wb1 = *(const bf16x8*)((const char*)woB + (((cc * 4 + q) * 64) + 1 * 16 + m) * 16);
    const bf16x8 wb2 = *(const bf16x8*)((const char*)woB + (((cc * 4 + q) * 64) + 2 * 16 + m) * 16);
    const bf16x8 wb3 = *(const bf16x8*)((const char*)woB + (((cc * 4 + q) * 64) + 3 * 16 + m) * 16);
    const f32x4 bin4 = *(const f32x4*)(b_in + cc * 16 + q * 4);
    const float* kvp = karrL + cc * 16 + q * 4;   // tap tp lives at kvp+tp*128

    // Hand-unrolled 6-row stream: h row rr feeds outputs py=rr-2..rr as
    // tap-row dy=rr-py. All indices literal; y0..y3 are named registers.
    f32x4 y0, y1, y2, y3;
    HROW(0, hL0, hM0, hR0);
    CINIT(y0, hL0, hM0, hR0);
    HROW(1, hL1, hM1, hR1);
    CMID (y0, hL1, hM1, hR1);
    CINIT(y1, hL1, hM1, hR1);
    HROW(2, hL2, hM2, hR2);
    CEMIT(0, y0, hL2, hM2, hR2);
    CMID (y1, hL2, hM2, hR2);
    CINIT(y2, hL2, hM2, hR2);
    HROW(3, hL3, hM3, hR3);
    CEMIT(1, y1, hL3, hM3, hR3);
    CMID (y2, hL3, hM3, hR3);
    CINIT(y3, hL3, hM3, hR3);
    HROW(4, hL4, hM4, hR4);
    CEMIT(2, y2, hL4, hM4, hR4);
    CMID (y3, hL4, hM4, hR4);
    HROW(5, hL5, hM5, hR5);
    CEMIT(3, y3, hL5, hM5, hR5);
  }
  __syncthreads();          // x_s / karr dead; bounce region reuses smem

  // ---- store via LDS bounce: aligned 64B f32x4 rows ----------------------
  float* smemF = (float*)smem;                      // [j][132] f32, halves of 8 rows
  const int c4 = t & 3, js = (t >> 2) & 63;
  const float bo = b_out[js];
  float* obase = out + ((size_t)(b * DIM_ + js) * HW_ + (ty * 16)) * HW_ + tx * 16 + c4 * 4;
#pragma unroll
  for (int half = 0; half < 2; ++half) {
    if ((wv >> 1) == half) {
#pragma unroll
      for (int py = 0; py < 4; ++py) {
        const int lrow = (wv * 4 + py) & 7;
#pragma unroll
        for (int nt = 0; nt < 4; ++nt)
          *(f32x4*)(smemF + (nt * 16 + m) * 132 + lrow * 16 + q * 4) = acc3[py][nt];
      }
    }
    __syncthreads();
#pragma unroll
    for (int lrow = 0; lrow < 8; ++lrow) {
      f32x4 v = *(const f32x4*)(smemF + js * 132 + lrow * 16 + c4 * 4);
      v += bo;
      *(f32x4*)(obase + (size_t)(half * 8 + lrow) * HW_) = v;
    }
    __syncthreads();
  }
}

// ---------------------------------------------------------------------------
extern "C" void kernel_launch(void* const* d_in, const int* in_sizes, int n_in,
                              void* d_out, int out_size, void* d_ws,
                              size_t ws_size, hipStream_t stream) {
  const float* x     = (const float*)d_in[0];
  const float* w_in  = (const float*)d_in[1];
  const float* b_in  = (const float*)d_in[2];
  const float* wg1   = (const float*)d_in[3];
  const float* bg1   = (const float*)d_in[4];
  const float* wg2   = (const float*)d_in[5];
  const float* bg2   = (const float*)d_in[6];
  const float* w_out = (const float*)d_in[7];
  const float* b_out = (const float*)d_in[8];
  float* out = (float*)d_out;

  char* ws = (char*)d_ws;
  bf16*  xT   = (bf16*)(ws + WS_XT);
  float* xsum = (float*)(ws + WS_XSUM);
  float* karr = (float*)(ws + WS_KARR);
  bf16*  wiA  = (bf16*)(ws + WS_WIA);
  bf16*  woB  = (bf16*)(ws + WS_WOB);

  dt_prepw<<<dim3(96), dim3(256), 0, stream>>>(w_in, w_out, wiA, woB, xsum);
  dt_prepx<<<dim3(PW_, B_), dim3(256), 0, stream>>>(x, xT, xsum);
  dt_kgen<<<dim3(B_), dim3(256), 0, stream>>>(xsum, w_in, b_in, wg1, bg1, wg2,
                                              bg2, karr);
  dt_kmain<<<dim3(12, 12, B_), dim3(256), 0, stream>>>(xT, wiA, woB, karr,
                                                       b_in, b_out, out);
}

// Round 6
// 326.807 us; speedup vs baseline: 1.4022x; 1.0088x over previous
//
#include <hip/hip_runtime.h>
#include <hip/hip_bf16.h>

// ---------------------------------------------------------------------------
// DynamicTransformer, round 10 = round 9 + tap hoist (36 -> 9 LDS reads/cc).
//
// Round-9 post-mortem: XCD pair-swizzle was a null (WRITE 153->162, kmain
// 152.9 vs 152.3us) -> store path rejected as the lever. Pipe budget per CU:
// MFMA 24K cyc/SIMD, VALU ~14K, LDS 10368 ds_read_b128 x 12cyc = 124K cyc
// (52us floor, largest pipe) at only 2 waves/SIMD -> tap-read latency chains
// (36 reads/cc, ds_read->FMA->af->MFMA) are the dominant exposed latency.
//
// Round-10: hoist the 9 tap f32x4 reads to the top of each cc iteration into
// NAMED registers k0_..k8_ (literal indices, rule-#20 safe). Tap reads drop
// 36->9 per cc; LDS floor 52->33us; per-emit latency chains vanish. Live set
// ~115 arch (vs proven-clean ~105 @r7, proven-spill ~139 @r0) — thin margin,
// so this is the ONLY change. Tripwire: FETCH/WRITE jump = spill = revert.
//
//  prepw : w_in / w_out -> bf16 MFMA fragment order; also zeros xsum
//  prepx : x -> xT (b, y+1, x+1, c) bf16, zero border, fused channel sums
//  kgen  : 256-thread, float4 dots; exact-fp32 generator -> karr[b][tap][o]
//  kmain : 16x16 aligned output tiles; h in f32 registers between proj_in
//          MFMA and depthwise conv; rotating y accumulators; LDS store bounce.
// ---------------------------------------------------------------------------

typedef __bf16 bf16;
typedef __bf16 bf16x4 __attribute__((ext_vector_type(4)));
typedef __bf16 bf16x8 __attribute__((ext_vector_type(8)));
typedef float  f32x4  __attribute__((ext_vector_type(4)));

#define B_   8
#define DIM_ 64
#define HID_ 128
#define HW_  192
#define PW_  194            // padded width/height of xT
#define XRS_ 196            // padded xr row stride (f32) in prepx

__device__ __forceinline__ void gl_lds16(const void* g, void* l) {
  __builtin_amdgcn_global_load_lds((__attribute__((address_space(1))) void*)(g),
                                   (__attribute__((address_space(3))) void*)(l),
                                   16, 0, 0);
}

// ws layout (bytes)
#define WS_XT    0u            // 8*194*194*64*2 = 38,539,264
#define WS_XSUM  38539264u     // 512 f32
#define WS_KARR  38541312u     // 8 * 9*128 f32 = 36,864
#define WS_WIA   38578176u     // 8192 bf16 = 16,384
#define WS_WOB   38594560u     // 16384 bf16 = 32,768

// ---------------------------------------------------------------------------
// prepw: w_in -> A-frag order [cc][kk][q][m][j] (o=16cc+m, c=32kk+8q+j)
//        w_out -> B-frag order [cc][q][j64][slot8]
// Block 0 additionally zeros xsum.
// ---------------------------------------------------------------------------
__global__ __launch_bounds__(256) void dt_prepw(const float* __restrict__ w_in,
                                                const float* __restrict__ w_out,
                                                bf16* __restrict__ wiA,
                                                bf16* __restrict__ woB,
                                                float* __restrict__ xsum) {
  if (blockIdx.x == 0) {
    xsum[threadIdx.x] = 0.f;
    xsum[threadIdx.x + 256] = 0.f;
  }
  int i = blockIdx.x * 256 + threadIdx.x;          // 0..24575
  if (i < 8192) {
    int j = i & 7, m = (i >> 3) & 15, q = (i >> 7) & 3, kk = (i >> 9) & 1, cc = i >> 10;
    int o = cc * 16 + m, c = kk * 32 + q * 8 + j;
    wiA[i] = (bf16)w_in[o * DIM_ + c];
  } else {
    int i2 = i - 8192;                             // 0..16383
    int sl = i2 & 7, j = (i2 >> 3) & 63, q = (i2 >> 9) & 3, cc = i2 >> 11;  // cc 0..7
    float v = (sl < 4) ? w_out[j * HID_ + cc * 16 + q * 4 + sl] : 0.f;
    woB[i2] = (bf16)v;
  }
}

// ---------------------------------------------------------------------------
// prepx: one block per (b, padded row yy). Interior rows: transpose 64x192
// f32 -> 192 px * 64c bf16 (via LDS), plus channel partial sums -> atomicAdd.
// Border rows / cols written as zeros. xr stride padded to 196 f32.
// ---------------------------------------------------------------------------
__global__ __launch_bounds__(256) void dt_prepx(const float* __restrict__ x,
                                                bf16* __restrict__ xT,
                                                float* __restrict__ xsum) {
  const int yy = blockIdx.x, b = blockIdx.y, t = threadIdx.x;
  bf16* xtrow = xT + ((size_t)(b * PW_ + yy)) * PW_ * DIM_;
  const bf16x8 z8 = {(bf16)0.f,(bf16)0.f,(bf16)0.f,(bf16)0.f,
                     (bf16)0.f,(bf16)0.f,(bf16)0.f,(bf16)0.f};
  if (yy == 0 || yy == PW_ - 1) {
    if (t < PW_) {
      bf16* dst = xtrow + t * DIM_;
#pragma unroll
      for (int c8 = 0; c8 < 8; ++c8) *(bf16x8*)(dst + c8 * 8) = z8;
    }
    return;
  }
  const int y = yy - 1;
  __shared__ float xr[DIM_ * XRS_];                // [c][px], stride 196
  const int c = t >> 2, qu = t & 3;
  const float4* rp = (const float4*)(x + ((size_t)(b * DIM_ + c) * HW_ + y) * HW_) + qu * 12;
  float s = 0.f;
#pragma unroll
  for (int i = 0; i < 12; ++i) {
    float4 v = rp[i];
    s += (v.x + v.y) + (v.z + v.w);
    ((float4*)xr)[c * 49 + qu * 12 + i] = v;       // 49 float4 = 196 f32 row
  }
  s += __shfl_down(s, 2);
  s += __shfl_down(s, 1);
  if ((t & 3) == 0) atomicAdd(xsum + b * DIM_ + c, s);
  __syncthreads();
  if (t < HW_) {
    const int px = t;
    bf16* dst = xtrow + (px + 1) * DIM_;
#pragma unroll
    for (int c8 = 0; c8 < 8; ++c8) {
      bf16x8 pk;
#pragma unroll
      for (int j2 = 0; j2 < 8; ++j2) pk[j2] = (bf16)xr[(c8 * 8 + j2) * XRS_ + px];
      *(bf16x8*)(dst + c8 * 8) = pk;
    }
  } else if (t == HW_ || t == HW_ + 1) {           // border cols xx=0, xx=193
    bf16* dst = xtrow + (size_t)(t - HW_) * (PW_ - 1) * DIM_;
#pragma unroll
    for (int c8 = 0; c8 < 8; ++c8) *(bf16x8*)(dst + c8 * 8) = z8;
  }
}

// ---------------------------------------------------------------------------
// kgen: exact fp32, 256 threads, float4 dot products.
// karr[b][tap][o], tap-major so kmain reads f32x4 over o.
// ---------------------------------------------------------------------------
__global__ __launch_bounds__(256) void dt_kgen(
    const float* __restrict__ xsum, const float* __restrict__ w_in,
    const float* __restrict__ b_in, const float* __restrict__ wg1,
    const float* __restrict__ bg1, const float* __restrict__ wg2,
    const float* __restrict__ bg2, float* __restrict__ karr) {
  const int b = blockIdx.x, t = threadIdx.x;
  __shared__ float xm[DIM_], hm[HID_], g[HID_];
  if (t < DIM_) xm[t] = xsum[b * DIM_ + t] * (1.f / (HW_ * HW_));
  __syncthreads();
  if (t < HID_) {
    float a = b_in[t];
    const float4* w = (const float4*)(w_in + t * DIM_);
#pragma unroll
    for (int c4 = 0; c4 < DIM_ / 4; ++c4) {
      float4 wv = w[c4];
      a += wv.x * xm[c4 * 4] + wv.y * xm[c4 * 4 + 1] +
           wv.z * xm[c4 * 4 + 2] + wv.w * xm[c4 * 4 + 3];
    }
    hm[t] = a;
  }
  __syncthreads();
  if (t < HID_) {
    float a = bg1[t];
    const float4* w = (const float4*)(wg1 + t * HID_);
#pragma unroll
    for (int c4 = 0; c4 < HID_ / 4; ++c4) {
      float4 wv = w[c4];
      a += wv.x * hm[c4 * 4] + wv.y * hm[c4 * 4 + 1] +
           wv.z * hm[c4 * 4 + 2] + wv.w * hm[c4 * 4 + 3];
    }
    g[t] = fmaxf(a, 0.f);
  }
  __syncthreads();
  for (int o = t; o < HID_ * 9; o += 256) {        // o = ch*9 + tp
    float s = bg2[o];
    const float4* w2 = (const float4*)(wg2 + (size_t)o * HID_);
#pragma unroll
    for (int c4 = 0; c4 < HID_ / 4; ++c4) {
      float4 wv = w2[c4];
      s += wv.x * g[c4 * 4] + wv.y * g[c4 * 4 + 1] +
           wv.z * g[c4 * 4 + 2] + wv.w * g[c4 * 4 + 3];
    }
    int ch = o / 9, tp = o - ch * 9;
    karr[b * 1152 + tp * HID_ + ch] = s;
  }
}

// ---------------------------------------------------------------------------
// kmain. Grid (12,12,8) raw, XCD pair-swizzle block decode (measured neutral,
// kept from round 9). 256 threads (4 waves); wave wv owns out rows 4wv..4wv+3.
// LDS: [0,41472) x_s; [41472,46080) karr; store bounce aliases [0,34048).
// __launch_bounds__(256,2): proven no-spill config.
// Taps: 9 f32x4 LDS reads hoisted to cc-top into NAMED regs k0_..k8_
// (36 regs); conv macros consume registers only -> 36->9 LDS reads per cc.
// ---------------------------------------------------------------------------
#define XROWB 2304
#define KOFF  41472

// h-row macro: proj_in MFMAs for the 3 shifted column windows of smem row
// (wv*4+RR), plus wave-uniform-row masked bias add. Declares HL/HM/HR.
#define HROW(RR, HL, HM, HR)                                                  \
  f32x4 HL, HM, HR;                                                           \
  do {                                                                        \
    const char* rbase_ = smem + (wv * 4 + (RR)) * XROWB + q * 288 + m * 16;   \
    const f32x4 z_ = 0.f;                                                     \
    bf16x8 xa_ = *(const bf16x8*)(rbase_);                                    \
    bf16x8 xb_ = *(const bf16x8*)(rbase_ + 1152);                             \
    HL = __builtin_amdgcn_mfma_f32_16x16x32_bf16(wa0, xa_, z_, 0, 0, 0);      \
    HL = __builtin_amdgcn_mfma_f32_16x16x32_bf16(wa1, xb_, HL, 0, 0, 0);      \
    xa_ = *(const bf16x8*)(rbase_ + 16);                                      \
    xb_ = *(const bf16x8*)(rbase_ + 1152 + 16);                               \
    HM = __builtin_amdgcn_mfma_f32_16x16x32_bf16(wa0, xa_, z_, 0, 0, 0);      \
    HM = __builtin_amdgcn_mfma_f32_16x16x32_bf16(wa1, xb_, HM, 0, 0, 0);      \
    xa_ = *(const bf16x8*)(rbase_ + 32);                                      \
    xb_ = *(const bf16x8*)(rbase_ + 1152 + 32);                               \
    HR = __builtin_amdgcn_mfma_f32_16x16x32_bf16(wa0, xa_, z_, 0, 0, 0);      \
    HR = __builtin_amdgcn_mfma_f32_16x16x32_bf16(wa1, xb_, HR, 0, 0, 0);      \
    if ((unsigned)(rowg0 + wv * 4 + (RR)) < (unsigned)HW_) {                  \
      HL += bin4 * mL; HM += bin4 * mM; HR += bin4 * mR;                      \
    }                                                                         \
  } while (0)

// conv steps consume the per-cc tap registers k0_..k8_ (no LDS access)
#define CINIT(Y, HL, HM, HR)                                                  \
  do { Y = k0_ * HL + k1_ * HM + k2_ * HR; } while (0)

#define CMID(Y, HL, HM, HR)                                                   \
  do { Y += k3_ * HL; Y += k4_ * HM; Y += k5_ * HR; } while (0)

#define CEMIT(PY, Y, HL, HM, HR)                                              \
  do { f32x4 v_ = Y + k6_ * HL + k7_ * HM + k8_ * HR;                         \
       float a0_ = v_[0], a1_ = v_[1], a2_ = v_[2], a3_ = v_[3];              \
       bf16x8 af_ = {(bf16)fmaxf(a0_, 0.1f * a0_),                            \
                     (bf16)fmaxf(a1_, 0.1f * a1_),                            \
                     (bf16)fmaxf(a2_, 0.1f * a2_),                            \
                     (bf16)fmaxf(a3_, 0.1f * a3_),                            \
                     (bf16)0.f, (bf16)0.f, (bf16)0.f, (bf16)0.f};             \
       acc3[PY][0] = __builtin_amdgcn_mfma_f32_16x16x32_bf16(af_, wb0, acc3[PY][0], 0, 0, 0); \
       acc3[PY][1] = __builtin_amdgcn_mfma_f32_16x16x32_bf16(af_, wb1, acc3[PY][1], 0, 0, 0); \
       acc3[PY][2] = __builtin_amdgcn_mfma_f32_16x16x32_bf16(af_, wb2, acc3[PY][2], 0, 0, 0); \
       acc3[PY][3] = __builtin_amdgcn_mfma_f32_16x16x32_bf16(af_, wb3, acc3[PY][3], 0, 0, 0); \
  } while (0)

__global__ __launch_bounds__(256, 2) void dt_kmain(
    const bf16* __restrict__ xT, const bf16* __restrict__ wiA,
    const bf16* __restrict__ woB, const float* __restrict__ karr,
    const float* __restrict__ b_in, const float* __restrict__ b_out,
    float* __restrict__ out) {
  __shared__ __attribute__((aligned(16))) char smem[46080];
  const int t = threadIdx.x;
  const int wv = t >> 6, lane = t & 63;
  const int q = lane >> 4, m = lane & 15;

  // XCD pair-swizzle: raw IDs {r, r+8} (same XCD) -> halves 0/1 of pair p.
  const int raw = blockIdx.x + 12 * blockIdx.y + 144 * blockIdx.z;  // 0..1151
  const int hf  = (raw >> 3) & 1;
  const int p   = (raw & 7) + ((raw >> 4) << 3);                    // 0..575
  const int pm6 = p % 6;
  const int tx  = 2 * pm6 + hf;
  const int ty  = (p / 6) % 12;
  const int b   = p / 72;

  // ---- stage x tile + karr via global_load_lds ---------------------------
  {
    const char* xbase = (const char*)xT +
        ((size_t)(b * PW_ + ty * 16) * PW_ + tx * 16) * (DIM_ * 2);
    for (int rr = wv; rr < 18; rr += 4) {
      const char* grow = xbase + (size_t)rr * (PW_ * DIM_ * 2);
      char* lrow = smem + rr * XROWB;
#pragma unroll
      for (int pp = 0; pp < 3; ++pp) {
        int idx = pp * 64 + lane;
        if (idx < 144) {
          int kq = (idx * 57) >> 10;        // idx / 18
          int px = idx - kq * 18;
          int goff = px * 128 + (kq >> 2) * 64 + (kq & 3) * 16;
          gl_lds16(grow + goff, lrow + pp * 1024);
        }
      }
    }
    const char* kg = (const char*)karr + b * 4608;
    gl_lds16(kg + (wv * 64 + lane) * 16, smem + KOFF + wv * 1024);
    if (wv == 0 && lane < 32)
      gl_lds16(kg + (256 + lane) * 16, smem + KOFF + 4096);
  }
  __syncthreads();

  const int rowg0 = ty * 16 - 1;
  const int colg0 = tx * 16 - 1;
  const float mL = ((unsigned)(colg0 + 0 + m) < (unsigned)HW_) ? 1.f : 0.f;
  const float mM = ((unsigned)(colg0 + 1 + m) < (unsigned)HW_) ? 1.f : 0.f;
  const float mR = ((unsigned)(colg0 + 2 + m) < (unsigned)HW_) ? 1.f : 0.f;

  f32x4 acc3[4][4];
#pragma unroll
  for (int a = 0; a < 4; ++a)
#pragma unroll
    for (int n = 0; n < 4; ++n) acc3[a][n] = 0.f;

  const float* karrL = (const float*)(smem + KOFF);

  for (int cc = 0; cc < 8; ++cc) {
    const bf16x8 wa0 = *(const bf16x8*)((const char*)wiA + ((cc * 2 + 0) * 4 + q) * 256 + m * 16);
    const bf16x8 wa1 = *(const bf16x8*)((const char*)wiA + ((cc * 2 + 1) * 4 + q) * 256 + m * 16);
    const bf16x8 wb0 = *(const bf16x8*)((const char*)woB + (((cc * 4 + q) * 64) + 0 * 16 + m) * 16);
    const bf16x8 wb1 = *(const bf16x8*)((const char*)woB + (((cc * 4 + q) * 64) + 1 * 16 + m) * 16);
    const bf16x8 wb2 = *(const bf16x8*)((const char*)woB + (((cc * 4 + q) * 64) + 2 * 16 + m) * 16);
    const bf16x8 wb3 = *(const bf16x8*)((const char*)woB + (((cc * 4 + q) * 64) + 3 * 16 + m) * 16);
    const f32x4 bin4 = *(const f32x4*)(b_in + cc * 16 + q * 4);
    const float* kvp = karrL + cc * 16 + q * 4;   // tap tp lives at kvp+tp*128

    // tap hoist: 9 f32x4 broadcast LDS reads -> named regs, once per cc
    const f32x4 k0_ = *(const f32x4*)(kvp + 0 * HID_);
    const f32x4 k1_ = *(const f32x4*)(kvp + 1 * HID_);
    const f32x4 k2_ = *(const f32x4*)(kvp + 2 * HID_);
    const f32x4 k3_ = *(const f32x4*)(kvp + 3 * HID_);
    const f32x4 k4_ = *(const f32x4*)(kvp + 4 * HID_);
    const f32x4 k5_ = *(const f32x4*)(kvp + 5 * HID_);
    const f32x4 k6_ = *(const f32x4*)(kvp + 6 * HID_);
    const f32x4 k7_ = *(const f32x4*)(kvp + 7 * HID_);
    const f32x4 k8_ = *(const f32x4*)(kvp + 8 * HID_);

    // Hand-unrolled 6-row stream: h row rr feeds outputs py=rr-2..rr as
    // tap-row dy=rr-py. All indices literal; y0..y3 are named registers.
    f32x4 y0, y1, y2, y3;
    HROW(0, hL0, hM0, hR0);
    CINIT(y0, hL0, hM0, hR0);
    HROW(1, hL1, hM1, hR1);
    CMID (y0, hL1, hM1, hR1);
    CINIT(y1, hL1, hM1, hR1);
    HROW(2, hL2, hM2, hR2);
    CEMIT(0, y0, hL2, hM2, hR2);
    CMID (y1, hL2, hM2, hR2);
    CINIT(y2, hL2, hM2, hR2);
    HROW(3, hL3, hM3, hR3);
    CEMIT(1, y1, hL3, hM3, hR3);
    CMID (y2, hL3, hM3, hR3);
    CINIT(y3, hL3, hM3, hR3);
    HROW(4, hL4, hM4, hR4);
    CEMIT(2, y2, hL4, hM4, hR4);
    CMID (y3, hL4, hM4, hR4);
    HROW(5, hL5, hM5, hR5);
    CEMIT(3, y3, hL5, hM5, hR5);
  }
  __syncthreads();          // x_s / karr dead; bounce region reuses smem

  // ---- store via LDS bounce: aligned 64B f32x4 rows ----------------------
  float* smemF = (float*)smem;                      // [j][132] f32, halves of 8 rows
  const int c4 = t & 3, js = (t >> 2) & 63;
  const float bo = b_out[js];
  float* obase = out + ((size_t)(b * DIM_ + js) * HW_ + (ty * 16)) * HW_ + tx * 16 + c4 * 4;
#pragma unroll
  for (int half = 0; half < 2; ++half) {
    if ((wv >> 1) == half) {
#pragma unroll
      for (int py = 0; py < 4; ++py) {
        const int lrow = (wv * 4 + py) & 7;
#pragma unroll
        for (int nt = 0; nt < 4; ++nt)
          *(f32x4*)(smemF + (nt * 16 + m) * 132 + lrow * 16 + q * 4) = acc3[py][nt];
      }
    }
    __syncthreads();
#pragma unroll
    for (int lrow = 0; lrow < 8; ++lrow) {
      f32x4 v = *(const f32x4*)(smemF + js * 132 + lrow * 16 + c4 * 4);
      v += bo;
      *(f32x4*)(obase + (size_t)(half * 8 + lrow) * HW_) = v;
    }
    __syncthreads();
  }
}

// ---------------------------------------------------------------------------
extern "C" void kernel_launch(void* const* d_in, const int* in_sizes, int n_in,
                              void* d_out, int out_size, void* d_ws,
                              size_t ws_size, hipStream_t stream) {
  const float* x     = (const float*)d_in[0];
  const float* w_in  = (const float*)d_in[1];
  const float* b_in  = (const float*)d_in[2];
  const float* wg1   = (const float*)d_in[3];
  const float* bg1   = (const float*)d_in[4];
  const float* wg2   = (const float*)d_in[5];
  const float* bg2   = (const float*)d_in[6];
  const float* w_out = (const float*)d_in[7];
  const float* b_out = (const float*)d_in[8];
  float* out = (float*)d_out;

  char* ws = (char*)d_ws;
  bf16*  xT   = (bf16*)(ws + WS_XT);
  float* xsum = (float*)(ws + WS_XSUM);
  float* karr = (float*)(ws + WS_KARR);
  bf16*  wiA  = (bf16*)(ws + WS_WIA);
  bf16*  woB  = (bf16*)(ws + WS_WOB);

  dt_prepw<<<dim3(96), dim3(256), 0, stream>>>(w_in, w_out, wiA, woB, xsum);
  dt_prepx<<<dim3(PW_, B_), dim3(256), 0, stream>>>(x, xT, xsum);
  dt_kgen<<<dim3(B_), dim3(256), 0, stream>>>(xsum, w_in, b_in, wg1, bg1, wg2,
                                              bg2, karr);
  dt_kmain<<<dim3(12, 12, B_), dim3(256), 0, stream>>>(xT, wiA, woB, karr,
                                                       b_in, b_out, out);
}